// Round 17
// baseline (275.756 us; speedup 1.0000x reference)
//
#include <hip/hip_runtime.h>
#include <math.h>

#define CONF_T 0.05f
#define NEGF  -1e10f
#define NCLS 16
#define TDET 100
#define CAP 4096
#define MSEL 512
#define MTOT (NCLS*TDET)    // 1600

template<int CTRL>
__device__ __forceinline__ void dpp_comb(float& s, int& j) {
  int si_ = __builtin_amdgcn_update_dpp(__float_as_int(s), __float_as_int(s),
                                        CTRL, 0xf, 0xf, false);
  int ji_ = __builtin_amdgcn_update_dpp(j, j, CTRL, 0xf, 0xf, false);
  float si = __int_as_float(si_);
  bool take = (si > s) || (si == s && ji_ < j);
  s = take ? si : s;
  j = take ? ji_ : j;
}
template<int CTRL>
__device__ __forceinline__ void dpp_max1(float& s) {
  int si_ = __builtin_amdgcn_update_dpp(__float_as_int(s), __float_as_int(s),
                                        CTRL, 0xf, 0xf, false);
  s = fmaxf(s, __int_as_float(si_));
}
template<int CTRL, int RM, bool BC>
__device__ __forceinline__ int dpp_mov0(int v) {
  return __builtin_amdgcn_update_dpp(0, v, CTRL, RM, 0xf, BC);
}
#define ROW_SHR1  0x111
#define ROW_SHR2  0x112
#define ROW_SHR4  0x114
#define ROW_SHR8  0x118
#define ROW_BC15  0x142
#define ROW_BC31  0x143

__device__ __forceinline__ void wave_comb64(float& s, int& j) {
  dpp_comb<ROW_SHR1>(s, j);
  dpp_comb<ROW_SHR2>(s, j);
  dpp_comb<ROW_SHR4>(s, j);
  dpp_comb<ROW_SHR8>(s, j);
  dpp_comb<ROW_BC15>(s, j);
  dpp_comb<ROW_BC31>(s, j);
}
__device__ __forceinline__ void wave_fmax64(float& s) {
  dpp_max1<ROW_SHR1>(s);
  dpp_max1<ROW_SHR2>(s);
  dpp_max1<ROW_SHR4>(s);
  dpp_max1<ROW_SHR8>(s);
  dpp_max1<ROW_BC15>(s);
  dpp_max1<ROW_BC31>(s);
}
__device__ __forceinline__ float rl_f(float v, int l) {
  return __int_as_float(__builtin_amdgcn_readlane(__float_as_int(v), l));
}

// ---------------- K1: class/score + per-chunk class counts (no box decode) ----------------
__global__ __launch_bounds__(256) void k_decode(
    const float* __restrict__ pred,
    float* __restrict__ score, int* __restrict__ cls,
    int* __restrict__ counts, int N, int nchunk)
{
  #pragma clang fp contract(off)
  const int b = blockIdx.x / nchunk;
  const int chunk = blockIdx.x % nchunk;
  const int t = threadIdx.x;
  const int n = chunk * 256 + t;

  __shared__ int hist[NCLS];
  if (t < NCLS) hist[t] = 0;
  __syncthreads();

  int v = -1;
  if (n < N) {
    const size_t i = (size_t)b * N + n;
    const float4* p4 = reinterpret_cast<const float4*>(pred + i * 20);
    float4 v1 = p4[1], v2 = p4[2], v3 = p4[3], v4 = p4[4];
    float lg[NCLS] = {v1.x, v1.y, v1.z, v1.w, v2.x, v2.y, v2.z, v2.w,
                      v3.x, v3.y, v3.z, v3.w, v4.x, v4.y, v4.z, v4.w};
    float best = -1.0f; int bi = 0;
    #pragma unroll
    for (int c = 0; c < NCLS; ++c) {
      float s = 1.0f / (1.0f + expf(-lg[c]));
      if (s > best) { best = s; bi = c; }
    }
    score[i] = best;
    v = (best >= CONF_T) ? bi : -1;
    cls[i] = v;
  }

  int lane = t & 63;
  #pragma unroll
  for (int c = 0; c < NCLS; ++c) {
    unsigned long long bl = __ballot(v == c);
    if (lane == 0 && bl) atomicAdd(&hist[c], __popcll(bl));
  }
  __syncthreads();
  if (t < NCLS) counts[(b * NCLS + t) * nchunk + chunk] = hist[t];
}

// ---------------- K2: stable scatter (fused scan) + on-the-fly box decode ----------------
__global__ __launch_bounds__(256) void k_scatter(
    const float* __restrict__ pred, const float* __restrict__ anch,
    const float* __restrict__ score, const int* __restrict__ cls,
    const int* __restrict__ counts,
    float* __restrict__ cand_sc, float* __restrict__ cand_bx, int* __restrict__ ktot,
    int N, int nchunk)
{
  #pragma clang fp contract(off)
  const int b = blockIdx.x / nchunk;
  const int chunk = blockIdx.x % nchunk;
  const int t = threadIdx.x;
  const int n = chunk * 256 + t;

  __shared__ int s_part[NCLS][17];
  __shared__ int s_ptot[NCLS][17];
  __shared__ int s_off[NCLS];
  __shared__ int wcnt[4][NCLS];

  {
    int c = t >> 4, part = t & 15;
    int su = 0, tot = 0;
    for (int ch = part; ch < nchunk; ch += 16) {
      int vv = counts[(b * NCLS + c) * nchunk + ch];
      tot += vv;
      su += (ch < chunk) ? vv : 0;
    }
    s_part[c][part] = su;
    s_ptot[c][part] = tot;
  }
  __syncthreads();
  if (t < NCLS) {
    int su = 0, tot = 0;
    #pragma unroll
    for (int i = 0; i < 16; ++i) { su += s_part[t][i]; tot += s_ptot[t][i]; }
    s_off[t] = su;
    if (chunk == 0) ktot[b * NCLS + t] = tot;
  }

  int v = (n < N) ? cls[(size_t)b * N + n] : -1;
  int lane = t & 63, w = t >> 6;
  int myrank = 0;
  #pragma unroll
  for (int c = 0; c < NCLS; ++c) {
    unsigned long long bl = __ballot(v == c);
    if (lane == 0) wcnt[w][c] = __popcll(bl);
    if (v == c) myrank = __popcll(bl & ((1ull << lane) - 1ull));
  }
  __syncthreads();
  if (v >= 0) {
    int pre = 0;
    #pragma unroll
    for (int i = 0; i < 4; ++i) if (i < w) pre += wcnt[i][v];
    int pos = s_off[v] + pre + myrank;
    if (pos < CAP) {
      const size_t i = (size_t)b * N + n;
      float4 p0 = *reinterpret_cast<const float4*>(pred + i * 20);
      float4 a = reinterpret_cast<const float4*>(anch)[n];  // cx, cy, w, h
      float xx = p0.x * a.z + a.x;
      float yy = p0.y * a.w + a.y;
      float wx = expf(p0.z) * a.z;
      float wy = expf(p0.w) * a.w;
      float hx = 0.5f * wx, hy = 0.5f * wy;
      float4 bx;
      bx.x = xx - hx; bx.y = yy - hy; bx.z = xx + hx; bx.w = yy + hy;
      int bc = b * NCLS + v;
      cand_sc[(size_t)bc * CAP + pos] = score[i];
      reinterpret_cast<float4*>(cand_bx)[(size_t)bc * CAP + pos] = bx;
    }
  }
}

// ---------------- K3: FUSED select + 8-wave 1-slot NMS (single-b128 pub) ----------------
__global__ __launch_bounds__(512) void k_nms(
    const float* __restrict__ cand_sc, const float* __restrict__ cand_bx,
    const int* __restrict__ ktot,
    float* __restrict__ out_box, float* __restrict__ out_sc, int* __restrict__ out_pick,
    int* __restrict__ flagOK)
{
  #pragma clang fp contract(off)
  const int bc = blockIdx.x;
  const int t = threadIdx.x;
  const int lane = t & 63, w = t >> 6;

  __shared__ int    hist[4096];
  __shared__ int    s_wsum[8];
  __shared__ int    s_T, s_thrbits;
  __shared__ int    s_cc[8][8];
  __shared__ float  s_csc[MSEL];
  __shared__ float4 sbx[MSEL];
  __shared__ float4 pub[2][16];      // idx w: {s, j, x1, y1}; idx 8+w: {x2, y2, -, -}
  __shared__ int    s_pk[TDET];
  __shared__ float  s_ps[TDET];

  int K = ktot[bc]; if (K > CAP) K = CAP;

  // ---- select phase ----
  for (int i = t; i < 4096; i += 512) hist[i] = 0;
  if (t == 0) { s_T = 4096; s_thrbits = 0; }
  __syncthreads();                                   // (1)

  float sc[8]; int key[8];
  #pragma unroll
  for (int k = 0; k < 8; ++k) {
    int j = k * 512 + t;
    if (j < K) {
      sc[k] = cand_sc[(size_t)bc * CAP + j];
      int bits = __float_as_int(sc[k]);
      int kk = (bits >> 11) - 0x7E000;          // [0.5,1.0) -> 0..4095, monotone
      kk = kk < 0 ? 0 : (kk > 4095 ? 4095 : kk);
      key[k] = kk;
      atomicAdd(&hist[kk], 1);
    } else { key[k] = -1; sc[k] = 0.0f; }
  }
  __syncthreads();                                   // (2)

  int h[8]; int loc = 0;
  #pragma unroll
  for (int u = 0; u < 8; ++u) { h[u] = hist[8 * t + u]; loc += h[u]; }
  int pf = loc;
  pf += dpp_mov0<ROW_SHR1, 0xf, true >(pf);
  pf += dpp_mov0<ROW_SHR2, 0xf, true >(pf);
  pf += dpp_mov0<ROW_SHR4, 0xf, true >(pf);
  pf += dpp_mov0<ROW_SHR8, 0xf, true >(pf);
  pf += dpp_mov0<ROW_BC15, 0xa, false>(pf);
  pf += dpp_mov0<ROW_BC31, 0xc, false>(pf);
  if (lane == 63) s_wsum[w] = pf;
  __syncthreads();                                   // (3)
  int base = 0, Kall = 0;
  #pragma unroll
  for (int i = 0; i < 8; ++i) {
    int v = s_wsum[i];
    Kall += v;
    if (i < w) base += v;
  }
  {
    int cLE = base + pf;                 // count of keys in bins <= 8t+7
    int run = Kall - (cLE - loc);        // cntGE(bin 8t)
    int cand = 0x7fffffff;
    #pragma unroll
    for (int u = 0; u < 8; ++u) {
      if (cand == 0x7fffffff && run <= MSEL) cand = 8 * t + u;
      run -= h[u];
    }
    if (cand != 0x7fffffff) atomicMin(&s_T, cand);
  }
  __syncthreads();                                   // (4)
  const int T = s_T;

  unsigned long long bl0, bl1, bl2, bl3, bl4, bl5, bl6, bl7;
  #define KEEPP(k) ((key[k] >= 0) && (key[k] >= T))
  bl0 = __ballot(KEEPP(0)); bl1 = __ballot(KEEPP(1));
  bl2 = __ballot(KEEPP(2)); bl3 = __ballot(KEEPP(3));
  bl4 = __ballot(KEEPP(4)); bl5 = __ballot(KEEPP(5));
  bl6 = __ballot(KEEPP(6)); bl7 = __ballot(KEEPP(7));
  if (lane == 0) {
    s_cc[w][0] = __popcll(bl0); s_cc[w][1] = __popcll(bl1);
    s_cc[w][2] = __popcll(bl2); s_cc[w][3] = __popcll(bl3);
    s_cc[w][4] = __popcll(bl4); s_cc[w][5] = __popcll(bl5);
    s_cc[w][6] = __popcll(bl6); s_cc[w][7] = __popcll(bl7);
  }
  #pragma unroll
  for (int k = 0; k < 8; ++k)
    if (key[k] >= 0 && key[k] < T) atomicMax(&s_thrbits, __float_as_int(sc[k]));
  __syncthreads();                                   // (5)

  int runpos = 0;
  #pragma unroll
  for (int k = 0; k < 8; ++k) {
    int pre = 0, tot = 0;
    #pragma unroll
    for (int i = 0; i < 8; ++i) {
      int c = s_cc[i][k];
      tot += c;
      if (i < w) pre += c;
    }
    unsigned long long blk = (k == 0) ? bl0 : (k == 1) ? bl1 : (k == 2) ? bl2 :
                             (k == 3) ? bl3 : (k == 4) ? bl4 : (k == 5) ? bl5 :
                             (k == 6) ? bl6 : bl7;
    if (KEEPP(k)) {
      int pos = runpos + pre + __popcll(blk & ((1ull << lane) - 1ull));
      s_csc[pos] = sc[k];
      sbx[pos] = reinterpret_cast<const float4*>(cand_bx)[(size_t)bc * CAP + k * 512 + t];
    }
    runpos += tot;
  }
  #undef KEEPP
  const int KM = runpos;                  // uniform, <= MSEL
  const float thr = (T == 0) ? -1e30f : __int_as_float(s_thrbits);
  __syncthreads();                                   // (6)

  // ---- NMS phase: ONE candidate per thread ----
  float  rsc0; float4 rbx0; float rar0;
  if (t < KM) {
    rsc0 = s_csc[t];
    rbx0 = sbx[t];
    rar0 = (rbx0.z - rbx0.x) * (rbx0.w - rbx0.y);
  } else {
    rsc0 = NEGF;
    rbx0.x = rbx0.y = rbx0.z = rbx0.w = 0.0f;
    rar0 = 0.0f;
  }

  // wave-uniform cached pub record (registers)
  float ps = NEGF, p1 = 0.0f, p2 = 0.0f, p3 = 0.0f, p4v = 0.0f;
  int   pj = 0;

  // publish: recompute only when a candidate in this wave changed; lane 0
  // writes the (wave-uniform) record. j == t lane-ordered: tie -> ctz(ballot).
  auto publish = [&](int par, bool recompute) {
    if (recompute) {
      float sm = rsc0;
      wave_fmax64(sm);
      ps = rl_f(sm, 63);
      unsigned long long msk = __ballot(rsc0 == ps);
      int jl = (int)__builtin_ctzll(msk);
      pj = (w << 6) | jl;
      p1 = rl_f(rbx0.x, jl); p2 = rl_f(rbx0.y, jl);
      p3 = rl_f(rbx0.z, jl); p4v = rl_f(rbx0.w, jl);
    }
    if (lane == 0) {
      float4 ra; ra.x = ps; ra.y = __int_as_float(pj); ra.z = p1; ra.w = p2;
      pub[par][w] = ra;
      float4 rb; rb.x = p3; rb.y = p4v; rb.z = 0.0f; rb.w = 0.0f;
      pub[par][8 + w] = rb;
    }
  };

  publish(0, true);

  bool ok = true, early = false;
  int total = 0;
  for (int iter = 0; iter < TDET; ++iter) {
    __syncthreads();                       // the ONLY barrier per iteration
    const int par = iter & 1;

    float4 ra = pub[par][lane & 15];       // ONE ds_read_b128
    // fmax over the 8 records (lanes 0..7 of row 0 hold them; 8..15 masked)
    float m = ((lane & 15) < 8) ? ra.x : NEGF;
    dpp_max1<ROW_SHR1>(m);
    dpp_max1<ROW_SHR2>(m);
    dpp_max1<ROW_SHR4>(m);
    const float ms = rl_f(m, 0);           // lane 0 = max(records 0..7)
    if (ms < CONF_T) { early = true; break; }
    ok = ok && (ms > thr);                 // exactness guard vs excluded set

    const int r = (int)__builtin_ctzll(
        __ballot(((lane & 15) < 8) && (ra.x == ms)));   // record idx 0..7
    const int mj = __builtin_amdgcn_readlane(__float_as_int(ra.y), r);
    const float px = rl_f(ra.z, r);
    const float py = rl_f(ra.w, r);
    const float pz = rl_f(ra.x, 8 + r);
    const float pw = rl_f(ra.y, 8 + r);
    if (t == 0) { s_pk[iter] = mj; s_ps[iter] = ms; }
    total = iter + 1;
    const float pa = (pz - px) * (pw - py);

    bool chg = false;
    if (rsc0 != NEGF) {
      if (t == mj) {
        rsc0 = NEGF; chg = true;
      } else if (!(px > rbx0.z || pz < rbx0.x || py > rbx0.w || pw < rbx0.y)) {
        float ltx = fmaxf(px, rbx0.x);
        float lty = fmaxf(py, rbx0.y);
        float rbv = fminf(pz, rbx0.z);
        float rby = fminf(pw, rbx0.w);
        float wx = fmaxf(rbv - ltx, 0.0f);
        float wy = fmaxf(rby - lty, 0.0f);
        float inter = wx * wy;
        if (inter > 0.0f) {                // inter==0 => score bit-identical
          float iou = inter / ((pa + rar0) - inter);
          float ns;
          if (iou > 0.5f) ns = NEGF;
          else {
            ns = rsc0 * expf((-10.0f * iou) * iou);
            if (ns < CONF_T) ns = NEGF;    // pruning: output-equivalent
          }
          rsc0 = ns; chg = true;
        }
      }
    }

    publish(par ^ 1, __ballot(chg) != 0ull);
  }
  if (early) ok = ok && (thr < CONF_T);

  __syncthreads();                          // s_pk/s_ps visible to all
  float* ob  = out_box  + (size_t)bc * TDET * 4;
  float* osc = out_sc   + (size_t)bc * TDET;
  int*   opk = out_pick + (size_t)bc * TDET;
  for (int rr = total + t; rr < TDET; rr += 512) opk[rr] = 0;
  if (t < total) {                          // total <= 100 < 512
    int jp = s_pk[t];
    float4 pb = sbx[jp];
    ob[t * 4 + 0] = pb.x; ob[t * 4 + 1] = pb.y;
    ob[t * 4 + 2] = pb.z; ob[t * 4 + 3] = pb.w;
    osc[t] = s_ps[t];
    opk[t] = 1;
  }
  if (t == 0) flagOK[bc] = ok ? 1 : 0;
}

// ---------------- K4: repair — exact batched NMS, gated on flag ----------------
__global__ __launch_bounds__(1024) void k_nms_full(
    const float* __restrict__ cand_sc, const float* __restrict__ cand_bx,
    const int* __restrict__ ktot, const int* __restrict__ flagOK,
    float* __restrict__ out_box, float* __restrict__ out_sc, int* __restrict__ out_pick)
{
  #pragma clang fp contract(off)
  const int bc = blockIdx.x;
  if (flagOK[bc]) return;
  const int t = threadIdx.x;
  const int lane = t & 63, w = t >> 6;

  __shared__ float4 s_box[CAP];
  __shared__ float  pub_s[64];
  __shared__ int    pub_j[64];
  __shared__ int    s_pkj[TDET];
  __shared__ float  s_pks[TDET];
  __shared__ int    s_info[2];

  int K = ktot[bc]; if (K > CAP) K = CAP;

  float  rsc[4];
  float4 rbx[4];
  float  rar[4];
  #pragma unroll
  for (int k = 0; k < 4; ++k) {
    int j = k * 1024 + t;
    if (j < K) {
      rsc[k] = cand_sc[(size_t)bc * CAP + j];
      float4 bb = reinterpret_cast<const float4*>(cand_bx)[(size_t)bc * CAP + j];
      rbx[k] = bb;
      s_box[j] = bb;
      rar[k] = (bb.z - bb.x) * (bb.w - bb.y);
    } else {
      rsc[k] = NEGF;
      rbx[k].x = rbx[k].y = rbx[k].z = rbx[k].w = 0.0f;
      float4 z; z.x = z.y = z.z = z.w = 0.0f;
      s_box[j] = z;
      rar[k] = 0.0f;
    }
  }

  auto publish4 = [&]() {
    float a0 = rsc[0], a1 = rsc[1], a2 = rsc[2], a3 = rsc[3];
    #pragma unroll
    for (int r = 0; r < 4; ++r) {
      float bs = a0; int bk = 0;
      if (a1 > bs) { bs = a1; bk = 1; }
      if (a2 > bs) { bs = a2; bk = 2; }
      if (a3 > bs) { bs = a3; bk = 3; }
      float s1 = bs; int j1 = bk * 1024 + t;
      wave_comb64(s1, j1);
      int ju = __builtin_amdgcn_readlane(j1, 63);
      if ((ju & 1023) == t) {
        int ex = ju >> 10;
        if (ex == 0) a0 = NEGF; else if (ex == 1) a1 = NEGF;
        else if (ex == 2) a2 = NEGF; else a3 = NEGF;
      }
      if (lane == 63) { pub_s[w * 4 + r] = s1; pub_j[w * 4 + r] = j1; }
    }
  };

  publish4();

  int total = 0;
  while (true) {
    __syncthreads();
    if (w == 0) {
      float es = pub_s[lane];
      int   ej = pub_j[lane];
      float4 eb = s_box[ej];
      float ear = (eb.z - eb.x) * (eb.w - eb.y);
      bool  eav = (es >= CONF_T);
      float hv = ((lane & 3) == 3) ? es : NEGF;
      wave_fmax64(hv);
      const float H = rl_f(hv, 63);
      int Rr = 0, dn = 0;
      while (true) {
        float cs = eav ? es : NEGF;
        int   cj = eav ? ej : 0x7fffffff;
        wave_comb64(cs, cj);
        float ms = rl_f(cs, 63);
        int   mj = __builtin_amdgcn_readlane(cj, 63);
        if (ms < CONF_T) { if (H < CONF_T) dn = 1; break; }
        if (Rr > 0 && !(ms > H)) break;
        if (lane == 0) { s_pkj[total + Rr] = mj; s_pks[total + Rr] = ms; }
        Rr++;
        if (total + Rr >= TDET) { dn = 1; break; }
        float4 pb = s_box[mj];
        float pa = (pb.z - pb.x) * (pb.w - pb.y);
        if (eav) {
          if (ej == mj) { eav = false; }
          else {
            float ltx = fmaxf(pb.x, eb.x);
            float lty = fmaxf(pb.y, eb.y);
            float rbv = fminf(pb.z, eb.z);
            float rby = fminf(pb.w, eb.w);
            float wx = fmaxf(rbv - ltx, 0.0f);
            float wy = fmaxf(rby - lty, 0.0f);
            float inter = wx * wy;
            if (inter > 0.0f) {
              float iou = inter / ((pa + ear) - inter);
              if (iou > 0.5f) { eav = false; }
              else {
                es = es * expf((-10.0f * iou) * iou);
                if (es < CONF_T) eav = false;
              }
            }
          }
        }
      }
      if (lane == 0) { s_info[0] = Rr; s_info[1] = dn; }
    }
    __syncthreads();

    const int Rr = s_info[0];
    const int dn = s_info[1];
    for (int r = 0; r < Rr; ++r) {
      const int jp = s_pkj[total + r];
      float4 pb = s_box[jp];
      float pa = (pb.z - pb.x) * (pb.w - pb.y);
      #pragma unroll
      for (int k = 0; k < 4; ++k) {
        float s = rsc[k];
        if (s == NEGF) continue;
        if (k * 1024 + t == jp) { rsc[k] = NEGF; continue; }
        float ltx = fmaxf(pb.x, rbx[k].x);
        float lty = fmaxf(pb.y, rbx[k].y);
        float rbv = fminf(pb.z, rbx[k].z);
        float rby = fminf(pb.w, rbx[k].w);
        float wx = fmaxf(rbv - ltx, 0.0f);
        float wy = fmaxf(rby - lty, 0.0f);
        float inter = wx * wy;
        if (inter > 0.0f) {
          float iou = inter / ((pa + rar[k]) - inter);
          float ns;
          if (iou > 0.5f) ns = NEGF;
          else {
            ns = s * expf((-10.0f * iou) * iou);
            if (ns < CONF_T) ns = NEGF;
          }
          rsc[k] = ns;
        }
      }
    }
    total += Rr;
    if (dn) break;
    publish4();
  }

  float* ob  = out_box  + (size_t)bc * TDET * 4;
  float* osc = out_sc   + (size_t)bc * TDET;
  int*   opk = out_pick + (size_t)bc * TDET;
  if (t < TDET) {
    if (t < total) {
      int jp = s_pkj[t];
      float4 pb = s_box[jp];
      ob[t * 4 + 0] = pb.x; ob[t * 4 + 1] = pb.y;
      ob[t * 4 + 2] = pb.z; ob[t * 4 + 3] = pb.w;
      osc[t] = s_pks[t];
      opk[t] = 1;
    } else {
      opk[t] = 0;
    }
  }
}

// ---------------- K5: per-batch compaction + stable top-100 (bitonic) ----------------
__global__ __launch_bounds__(1024) void k_post(
    const float* __restrict__ out_box, const float* __restrict__ out_sc,
    const int* __restrict__ out_pick,
    float* __restrict__ out, int B)
{
  #pragma clang fp contract(off)
  const int b = blockIdx.x;
  const int t = threadIdx.x;

  __shared__ float p_sc[MTOT];
  __shared__ float p_bx[MTOT * 4];
  __shared__ unsigned char p_v[MTOT];
  __shared__ float q_sc[MTOT];
  __shared__ short q_m[MTOT];
  __shared__ int s_wtot[16];
  __shared__ unsigned long long s_key[2048];

  for (int m = t; m < MTOT; m += 1024) {
    int c = m / TDET, tt = m % TDET;
    int lanebc = b * NCLS + c;
    int pk = out_pick[(size_t)lanebc * TDET + tt];
    p_v[m] = (unsigned char)pk;
    if (pk) {
      p_sc[m] = out_sc[(size_t)lanebc * TDET + tt];
      p_bx[m * 4 + 0] = out_box[((size_t)lanebc * TDET + tt) * 4 + 0];
      p_bx[m * 4 + 1] = out_box[((size_t)lanebc * TDET + tt) * 4 + 1];
      p_bx[m * 4 + 2] = out_box[((size_t)lanebc * TDET + tt) * 4 + 2];
      p_bx[m * 4 + 3] = out_box[((size_t)lanebc * TDET + tt) * 4 + 3];
    } else {
      p_sc[m] = 0.0f;
      p_bx[m * 4 + 0] = 0.0f; p_bx[m * 4 + 1] = 0.0f;
      p_bx[m * 4 + 2] = 0.0f; p_bx[m * 4 + 3] = 0.0f;
    }
  }
  __syncthreads();

  int running = 0;
  for (int base = 0; base < MTOT; base += 1024) {
    int m = base + t;
    bool v = (m < MTOT) && p_v[m];
    unsigned long long ball = __ballot(v);
    int lane = t & 63, w = t >> 6;
    if (lane == 0) s_wtot[w] = __popcll(ball);
    __syncthreads();
    int off = 0, tot = 0;
    #pragma unroll
    for (int i = 0; i < 16; ++i) {
      int ci = s_wtot[i];
      if (i < w) off += ci;
      tot += ci;
    }
    if (v) {
      int wpre = __popcll(ball & ((1ull << lane) - 1ull));
      int j = running + off + wpre;
      q_sc[j] = p_sc[m];
      q_m[j] = (short)m;
    }
    running += tot;
    __syncthreads();
  }
  int nv = running;
  bool over = nv > TDET;

  if (over) {
    for (int e = t; e < 2048; e += 1024) {
      unsigned long long kk = 0;
      if (e < nv) {
        unsigned int sb = __float_as_uint(q_sc[e]);
        kk = ((unsigned long long)sb << 32) | (unsigned int)(~e);
      }
      s_key[e] = ~kk;
    }
    for (int kk2 = 2; kk2 <= 2048; kk2 <<= 1) {
      for (int j = kk2 >> 1; j > 0; j >>= 1) {
        __syncthreads();
        int e = ((t & ~(j - 1)) << 1) | (t & (j - 1));
        int q = e | j;
        unsigned long long a = s_key[e], bb = s_key[q];
        bool up = ((e & kk2) == 0);
        bool sw = up ? (a > bb) : (a < bb);
        if (sw) { s_key[e] = bb; s_key[q] = a; }
      }
    }
    __syncthreads();
  }

  int vd = nv < TDET ? nv : TDET;
  int base_box = B;
  int base_sc  = B + B * TDET * 4;
  int base_cl  = base_sc + B * TDET;
  if (t == 0) out[b] = (float)vd;
  if (t < TDET) {
    float sc = 0.0f, cl = -1.0f, b0 = 0.0f, b1 = 0.0f, b2 = 0.0f, b3 = 0.0f;
    int p = -1;
    if (t < nv) p = over ? (int)(unsigned int)s_key[t] : t;
    if (p >= 0) {
      int m = q_m[p];
      sc = q_sc[p];
      cl = (float)(m / TDET);
      b0 = p_bx[m * 4 + 0]; b1 = p_bx[m * 4 + 1];
      b2 = p_bx[m * 4 + 2]; b3 = p_bx[m * 4 + 3];
    }
    int o = b * TDET + t;
    out[base_box + o * 4 + 0] = b0;
    out[base_box + o * 4 + 1] = b1;
    out[base_box + o * 4 + 2] = b2;
    out[base_box + o * 4 + 3] = b3;
    out[base_sc + o] = sc;
    out[base_cl + o] = cl;
  }
}

extern "C" void kernel_launch(void* const* d_in, const int* in_sizes, int n_in,
                              void* d_out, int out_size, void* d_ws, size_t ws_size,
                              hipStream_t stream) {
  const float* pred = (const float*)d_in[0];
  const float* anch = (const float*)d_in[1];
  int N  = in_sizes[1] / 4;       // 49104
  int BN = in_sizes[0] / 20;      // B*N
  int B  = BN / N;                // 4
  int nchunk = (N + 255) / 256;   // 192
  int NBC = B * NCLS;             // 64

  char* ws = (char*)d_ws;
  size_t off = 0;
  // float4-accessed arrays first (16B alignment)
  float* candbx = (float*)(ws + off); off += (size_t)NBC * CAP * 4 * sizeof(float);
  float* obox   = (float*)(ws + off); off += (size_t)NBC * TDET * 4 * sizeof(float);
  float* score  = (float*)(ws + off); off += (size_t)BN * sizeof(float);
  float* candsc = (float*)(ws + off); off += (size_t)NBC * CAP * sizeof(float);
  float* osc    = (float*)(ws + off); off += (size_t)NBC * TDET * sizeof(float);
  int*   cls    = (int*)(ws + off);   off += (size_t)BN * sizeof(int);
  int*   counts = (int*)(ws + off);   off += (size_t)NBC * nchunk * sizeof(int);
  int*   ktot   = (int*)(ws + off);   off += (size_t)NBC * sizeof(int);
  int*   opick  = (int*)(ws + off);   off += (size_t)NBC * TDET * sizeof(int);
  int*   flagOK = (int*)(ws + off);   off += (size_t)NBC * sizeof(int);

  k_decode<<<B * nchunk, 256, 0, stream>>>(pred, score, cls, counts, N, nchunk);
  k_scatter<<<B * nchunk, 256, 0, stream>>>(pred, anch, score, cls, counts,
                                            candsc, candbx, ktot, N, nchunk);
  k_nms<<<NBC, 512, 0, stream>>>(candsc, candbx, ktot, obox, osc, opick, flagOK);
  k_nms_full<<<NBC, 1024, 0, stream>>>(candsc, candbx, ktot, flagOK, obox, osc, opick);
  k_post<<<B, 1024, 0, stream>>>(obox, osc, opick, (float*)d_out, B);
}

// Round 18
// 135.725 us; speedup vs baseline: 2.0317x; 2.0317x over previous
//
#include <hip/hip_runtime.h>
#include <math.h>

#define CONF_T 0.05f
#define NEGF  -1e10f
#define NCLS 16
#define TDET 100
#define CAP 4096
#define MSEL 512
#define MTOT (NCLS*TDET)    // 1600

template<int CTRL>
__device__ __forceinline__ void dpp_comb(float& s, int& j) {
  int si_ = __builtin_amdgcn_update_dpp(__float_as_int(s), __float_as_int(s),
                                        CTRL, 0xf, 0xf, false);
  int ji_ = __builtin_amdgcn_update_dpp(j, j, CTRL, 0xf, 0xf, false);
  float si = __int_as_float(si_);
  bool take = (si > s) || (si == s && ji_ < j);
  s = take ? si : s;
  j = take ? ji_ : j;
}
template<int CTRL>
__device__ __forceinline__ void dpp_max1(float& s) {
  int si_ = __builtin_amdgcn_update_dpp(__float_as_int(s), __float_as_int(s),
                                        CTRL, 0xf, 0xf, false);
  s = fmaxf(s, __int_as_float(si_));
}
template<int CTRL, int RM, bool BC>
__device__ __forceinline__ int dpp_mov0(int v) {
  return __builtin_amdgcn_update_dpp(0, v, CTRL, RM, 0xf, BC);
}
#define ROW_SHR1  0x111
#define ROW_SHR2  0x112
#define ROW_SHR4  0x114
#define ROW_SHR8  0x118
#define ROW_BC15  0x142
#define ROW_BC31  0x143

__device__ __forceinline__ void wave_comb64(float& s, int& j) {
  dpp_comb<ROW_SHR1>(s, j);
  dpp_comb<ROW_SHR2>(s, j);
  dpp_comb<ROW_SHR4>(s, j);
  dpp_comb<ROW_SHR8>(s, j);
  dpp_comb<ROW_BC15>(s, j);
  dpp_comb<ROW_BC31>(s, j);
}
__device__ __forceinline__ void wave_fmax64(float& s) {
  dpp_max1<ROW_SHR1>(s);
  dpp_max1<ROW_SHR2>(s);
  dpp_max1<ROW_SHR4>(s);
  dpp_max1<ROW_SHR8>(s);
  dpp_max1<ROW_BC15>(s);
  dpp_max1<ROW_BC31>(s);
}
__device__ __forceinline__ float rl_f(float v, int l) {
  return __int_as_float(__builtin_amdgcn_readlane(__float_as_int(v), l));
}

// ---------------- K1: class/score + per-chunk class counts (no box decode) ----------------
__global__ __launch_bounds__(256) void k_decode(
    const float* __restrict__ pred,
    float* __restrict__ score, int* __restrict__ cls,
    int* __restrict__ counts, int N, int nchunk)
{
  #pragma clang fp contract(off)
  const int b = blockIdx.x / nchunk;
  const int chunk = blockIdx.x % nchunk;
  const int t = threadIdx.x;
  const int n = chunk * 256 + t;

  __shared__ int hist[NCLS];
  if (t < NCLS) hist[t] = 0;
  __syncthreads();

  int v = -1;
  if (n < N) {
    const size_t i = (size_t)b * N + n;
    const float4* p4 = reinterpret_cast<const float4*>(pred + i * 20);
    float4 v1 = p4[1], v2 = p4[2], v3 = p4[3], v4 = p4[4];
    float lg[NCLS] = {v1.x, v1.y, v1.z, v1.w, v2.x, v2.y, v2.z, v2.w,
                      v3.x, v3.y, v3.z, v3.w, v4.x, v4.y, v4.z, v4.w};
    float best = -1.0f; int bi = 0;
    #pragma unroll
    for (int c = 0; c < NCLS; ++c) {
      float s = 1.0f / (1.0f + expf(-lg[c]));
      if (s > best) { best = s; bi = c; }
    }
    score[i] = best;
    v = (best >= CONF_T) ? bi : -1;
    cls[i] = v;
  }

  int lane = t & 63;
  #pragma unroll
  for (int c = 0; c < NCLS; ++c) {
    unsigned long long bl = __ballot(v == c);
    if (lane == 0 && bl) atomicAdd(&hist[c], __popcll(bl));
  }
  __syncthreads();
  if (t < NCLS) counts[(b * NCLS + t) * nchunk + chunk] = hist[t];
}

// ---------------- K2: stable scatter (fused scan) + on-the-fly box decode ----------------
__global__ __launch_bounds__(256) void k_scatter(
    const float* __restrict__ pred, const float* __restrict__ anch,
    const float* __restrict__ score, const int* __restrict__ cls,
    const int* __restrict__ counts,
    float* __restrict__ cand_sc, float* __restrict__ cand_bx, int* __restrict__ ktot,
    int N, int nchunk)
{
  #pragma clang fp contract(off)
  const int b = blockIdx.x / nchunk;
  const int chunk = blockIdx.x % nchunk;
  const int t = threadIdx.x;
  const int n = chunk * 256 + t;

  __shared__ int s_part[NCLS][17];
  __shared__ int s_ptot[NCLS][17];
  __shared__ int s_off[NCLS];
  __shared__ int wcnt[4][NCLS];

  {
    int c = t >> 4, part = t & 15;
    int su = 0, tot = 0;
    for (int ch = part; ch < nchunk; ch += 16) {
      int vv = counts[(b * NCLS + c) * nchunk + ch];
      tot += vv;
      su += (ch < chunk) ? vv : 0;
    }
    s_part[c][part] = su;
    s_ptot[c][part] = tot;
  }
  __syncthreads();
  if (t < NCLS) {
    int su = 0, tot = 0;
    #pragma unroll
    for (int i = 0; i < 16; ++i) { su += s_part[t][i]; tot += s_ptot[t][i]; }
    s_off[t] = su;
    if (chunk == 0) ktot[b * NCLS + t] = tot;
  }

  int v = (n < N) ? cls[(size_t)b * N + n] : -1;
  int lane = t & 63, w = t >> 6;
  int myrank = 0;
  #pragma unroll
  for (int c = 0; c < NCLS; ++c) {
    unsigned long long bl = __ballot(v == c);
    if (lane == 0) wcnt[w][c] = __popcll(bl);
    if (v == c) myrank = __popcll(bl & ((1ull << lane) - 1ull));
  }
  __syncthreads();
  if (v >= 0) {
    int pre = 0;
    #pragma unroll
    for (int i = 0; i < 4; ++i) if (i < w) pre += wcnt[i][v];
    int pos = s_off[v] + pre + myrank;
    if (pos < CAP) {
      const size_t i = (size_t)b * N + n;
      float4 p0 = *reinterpret_cast<const float4*>(pred + i * 20);
      float4 a = reinterpret_cast<const float4*>(anch)[n];  // cx, cy, w, h
      float xx = p0.x * a.z + a.x;
      float yy = p0.y * a.w + a.y;
      float wx = expf(p0.z) * a.z;
      float wy = expf(p0.w) * a.w;
      float hx = 0.5f * wx, hy = 0.5f * wy;
      float4 bx;
      bx.x = xx - hx; bx.y = yy - hy; bx.z = xx + hx; bx.w = yy + hy;
      int bc = b * NCLS + v;
      cand_sc[(size_t)bc * CAP + pos] = score[i];
      reinterpret_cast<float4*>(cand_bx)[(size_t)bc * CAP + pos] = bx;
    }
  }
}

// ---------------- K3: FUSED select + 8-wave 1-slot NMS (single-b128 pub) ----------------
__global__ __launch_bounds__(512) void k_nms(
    const float* __restrict__ cand_sc, const float* __restrict__ cand_bx,
    const int* __restrict__ ktot,
    float* __restrict__ out_box, float* __restrict__ out_sc, int* __restrict__ out_pick,
    int* __restrict__ flagOK)
{
  #pragma clang fp contract(off)
  const int bc = blockIdx.x;
  const int t = threadIdx.x;
  const int lane = t & 63, w = t >> 6;

  __shared__ int    hist[4096];
  __shared__ int    s_wsum[8];
  __shared__ int    s_T, s_thrbits;
  __shared__ int    s_cc[8][8];
  __shared__ float  s_csc[MSEL];
  __shared__ float4 sbx[MSEL];
  __shared__ float4 pub[2][16];      // idx w: {s, j, x1, y1}; idx 8+w: {x2, y2, -, -}
  __shared__ int    s_pk[TDET];
  __shared__ float  s_ps[TDET];

  int K = ktot[bc]; if (K > CAP) K = CAP;

  // ---- select phase ----
  for (int i = t; i < 4096; i += 512) hist[i] = 0;
  if (t == 0) { s_T = 4096; s_thrbits = 0; }
  __syncthreads();                                   // (1)

  float sc[8]; int key[8];
  #pragma unroll
  for (int k = 0; k < 8; ++k) {
    int j = k * 512 + t;
    if (j < K) {
      sc[k] = cand_sc[(size_t)bc * CAP + j];
      int bits = __float_as_int(sc[k]);
      int kk = (bits >> 11) - 0x7E000;          // [0.5,1.0) -> 0..4095, monotone
      kk = kk < 0 ? 0 : (kk > 4095 ? 4095 : kk);
      key[k] = kk;
      atomicAdd(&hist[kk], 1);
    } else { key[k] = -1; sc[k] = 0.0f; }
  }
  __syncthreads();                                   // (2)

  int h[8]; int loc = 0;
  #pragma unroll
  for (int u = 0; u < 8; ++u) { h[u] = hist[8 * t + u]; loc += h[u]; }
  int pf = loc;
  pf += dpp_mov0<ROW_SHR1, 0xf, true >(pf);
  pf += dpp_mov0<ROW_SHR2, 0xf, true >(pf);
  pf += dpp_mov0<ROW_SHR4, 0xf, true >(pf);
  pf += dpp_mov0<ROW_SHR8, 0xf, true >(pf);
  pf += dpp_mov0<ROW_BC15, 0xa, false>(pf);
  pf += dpp_mov0<ROW_BC31, 0xc, false>(pf);
  if (lane == 63) s_wsum[w] = pf;
  __syncthreads();                                   // (3)
  int base = 0, Kall = 0;
  #pragma unroll
  for (int i = 0; i < 8; ++i) {
    int v = s_wsum[i];
    Kall += v;
    if (i < w) base += v;
  }
  {
    int cLE = base + pf;                 // count of keys in bins <= 8t+7
    int run = Kall - (cLE - loc);        // cntGE(bin 8t)
    int cand = 0x7fffffff;
    #pragma unroll
    for (int u = 0; u < 8; ++u) {
      if (cand == 0x7fffffff && run <= MSEL) cand = 8 * t + u;
      run -= h[u];
    }
    if (cand != 0x7fffffff) atomicMin(&s_T, cand);
  }
  __syncthreads();                                   // (4)
  const int T = s_T;

  unsigned long long bl0, bl1, bl2, bl3, bl4, bl5, bl6, bl7;
  #define KEEPP(k) ((key[k] >= 0) && (key[k] >= T))
  bl0 = __ballot(KEEPP(0)); bl1 = __ballot(KEEPP(1));
  bl2 = __ballot(KEEPP(2)); bl3 = __ballot(KEEPP(3));
  bl4 = __ballot(KEEPP(4)); bl5 = __ballot(KEEPP(5));
  bl6 = __ballot(KEEPP(6)); bl7 = __ballot(KEEPP(7));
  if (lane == 0) {
    s_cc[w][0] = __popcll(bl0); s_cc[w][1] = __popcll(bl1);
    s_cc[w][2] = __popcll(bl2); s_cc[w][3] = __popcll(bl3);
    s_cc[w][4] = __popcll(bl4); s_cc[w][5] = __popcll(bl5);
    s_cc[w][6] = __popcll(bl6); s_cc[w][7] = __popcll(bl7);
  }
  #pragma unroll
  for (int k = 0; k < 8; ++k)
    if (key[k] >= 0 && key[k] < T) atomicMax(&s_thrbits, __float_as_int(sc[k]));
  __syncthreads();                                   // (5)

  int runpos = 0;
  #pragma unroll
  for (int k = 0; k < 8; ++k) {
    int pre = 0, tot = 0;
    #pragma unroll
    for (int i = 0; i < 8; ++i) {
      int c = s_cc[i][k];
      tot += c;
      if (i < w) pre += c;
    }
    unsigned long long blk = (k == 0) ? bl0 : (k == 1) ? bl1 : (k == 2) ? bl2 :
                             (k == 3) ? bl3 : (k == 4) ? bl4 : (k == 5) ? bl5 :
                             (k == 6) ? bl6 : bl7;
    if (KEEPP(k)) {
      int pos = runpos + pre + __popcll(blk & ((1ull << lane) - 1ull));
      s_csc[pos] = sc[k];
      sbx[pos] = reinterpret_cast<const float4*>(cand_bx)[(size_t)bc * CAP + k * 512 + t];
    }
    runpos += tot;
  }
  #undef KEEPP
  const int KM = runpos;                  // uniform, <= MSEL
  const float thr = (T == 0) ? -1e30f : __int_as_float(s_thrbits);
  __syncthreads();                                   // (6)

  // ---- NMS phase: ONE candidate per thread ----
  float  rsc0; float4 rbx0; float rar0;
  if (t < KM) {
    rsc0 = s_csc[t];
    rbx0 = sbx[t];
    rar0 = (rbx0.z - rbx0.x) * (rbx0.w - rbx0.y);
  } else {
    rsc0 = NEGF;
    rbx0.x = rbx0.y = rbx0.z = rbx0.w = 0.0f;
    rar0 = 0.0f;
  }

  // wave-uniform cached pub record (registers)
  float ps = NEGF, p1 = 0.0f, p2 = 0.0f, p3 = 0.0f, p4v = 0.0f;
  int   pj = 0;

  auto publish = [&](int par, bool recompute) {
    if (recompute) {
      float sm = rsc0;
      wave_fmax64(sm);
      ps = rl_f(sm, 63);
      unsigned long long msk = __ballot(rsc0 == ps);
      int jl = (int)__builtin_ctzll(msk);
      pj = (w << 6) | jl;
      p1 = rl_f(rbx0.x, jl); p2 = rl_f(rbx0.y, jl);
      p3 = rl_f(rbx0.z, jl); p4v = rl_f(rbx0.w, jl);
    }
    if (lane == 0) {
      float4 ra; ra.x = ps; ra.y = __int_as_float(pj); ra.z = p1; ra.w = p2;
      pub[par][w] = ra;
      float4 rb; rb.x = p3; rb.y = p4v; rb.z = 0.0f; rb.w = 0.0f;
      pub[par][8 + w] = rb;
    }
  };

  publish(0, true);

  bool ok = true, early = false;
  int total = 0;
  for (int iter = 0; iter < TDET; ++iter) {
    __syncthreads();                       // the ONLY barrier per iteration
    const int par = iter & 1;

    float4 ra = pub[par][lane & 15];       // ONE ds_read_b128
    // fmax over the 8 records; ROW_SHR moves values toward HIGHER lanes:
    // after shr1+shr2+shr4, lane 7 (of each 16-row) = max of lanes 0..7.
    float m = ((lane & 15) < 8) ? ra.x : NEGF;
    dpp_max1<ROW_SHR1>(m);
    dpp_max1<ROW_SHR2>(m);
    dpp_max1<ROW_SHR4>(m);
    const float ms = rl_f(m, 7);           // lane 7 = max(records 0..7)  [FIX]
    if (ms < CONF_T) { early = true; break; }
    ok = ok && (ms > thr);                 // exactness guard vs excluded set

    const int r = (int)__builtin_ctzll(
        __ballot(((lane & 15) < 8) && (ra.x == ms)));   // record idx 0..7
    const int mj = __builtin_amdgcn_readlane(__float_as_int(ra.y), r);
    const float px = rl_f(ra.z, r);
    const float py = rl_f(ra.w, r);
    const float pz = rl_f(ra.x, 8 + r);
    const float pw = rl_f(ra.y, 8 + r);
    if (t == 0) { s_pk[iter] = mj; s_ps[iter] = ms; }
    total = iter + 1;
    const float pa = (pz - px) * (pw - py);

    bool chg = false;
    if (rsc0 != NEGF) {
      if (t == mj) {
        rsc0 = NEGF; chg = true;
      } else if (!(px > rbx0.z || pz < rbx0.x || py > rbx0.w || pw < rbx0.y)) {
        float ltx = fmaxf(px, rbx0.x);
        float lty = fmaxf(py, rbx0.y);
        float rbv = fminf(pz, rbx0.z);
        float rby = fminf(pw, rbx0.w);
        float wx = fmaxf(rbv - ltx, 0.0f);
        float wy = fmaxf(rby - lty, 0.0f);
        float inter = wx * wy;
        if (inter > 0.0f) {                // inter==0 => score bit-identical
          float iou = inter / ((pa + rar0) - inter);
          float ns;
          if (iou > 0.5f) ns = NEGF;
          else {
            ns = rsc0 * expf((-10.0f * iou) * iou);
            if (ns < CONF_T) ns = NEGF;    // pruning: output-equivalent
          }
          rsc0 = ns; chg = true;
        }
      }
    }

    publish(par ^ 1, __ballot(chg) != 0ull);
  }
  if (early) ok = ok && (thr < CONF_T);

  __syncthreads();                          // s_pk/s_ps visible to all
  float* ob  = out_box  + (size_t)bc * TDET * 4;
  float* osc = out_sc   + (size_t)bc * TDET;
  int*   opk = out_pick + (size_t)bc * TDET;
  for (int rr = total + t; rr < TDET; rr += 512) opk[rr] = 0;
  if (t < total) {                          // total <= 100 < 512
    int jp = s_pk[t];
    float4 pb = sbx[jp];
    ob[t * 4 + 0] = pb.x; ob[t * 4 + 1] = pb.y;
    ob[t * 4 + 2] = pb.z; ob[t * 4 + 3] = pb.w;
    osc[t] = s_ps[t];
    opk[t] = 1;
  }
  if (t == 0) flagOK[bc] = ok ? 1 : 0;
}

// ---------------- K4: repair — exact batched NMS, gated on flag ----------------
__global__ __launch_bounds__(1024) void k_nms_full(
    const float* __restrict__ cand_sc, const float* __restrict__ cand_bx,
    const int* __restrict__ ktot, const int* __restrict__ flagOK,
    float* __restrict__ out_box, float* __restrict__ out_sc, int* __restrict__ out_pick)
{
  #pragma clang fp contract(off)
  const int bc = blockIdx.x;
  if (flagOK[bc]) return;
  const int t = threadIdx.x;
  const int lane = t & 63, w = t >> 6;

  __shared__ float4 s_box[CAP];
  __shared__ float  pub_s[64];
  __shared__ int    pub_j[64];
  __shared__ int    s_pkj[TDET];
  __shared__ float  s_pks[TDET];
  __shared__ int    s_info[2];

  int K = ktot[bc]; if (K > CAP) K = CAP;

  float  rsc[4];
  float4 rbx[4];
  float  rar[4];
  #pragma unroll
  for (int k = 0; k < 4; ++k) {
    int j = k * 1024 + t;
    if (j < K) {
      rsc[k] = cand_sc[(size_t)bc * CAP + j];
      float4 bb = reinterpret_cast<const float4*>(cand_bx)[(size_t)bc * CAP + j];
      rbx[k] = bb;
      s_box[j] = bb;
      rar[k] = (bb.z - bb.x) * (bb.w - bb.y);
    } else {
      rsc[k] = NEGF;
      rbx[k].x = rbx[k].y = rbx[k].z = rbx[k].w = 0.0f;
      float4 z; z.x = z.y = z.z = z.w = 0.0f;
      s_box[j] = z;
      rar[k] = 0.0f;
    }
  }

  auto publish4 = [&]() {
    float a0 = rsc[0], a1 = rsc[1], a2 = rsc[2], a3 = rsc[3];
    #pragma unroll
    for (int r = 0; r < 4; ++r) {
      float bs = a0; int bk = 0;
      if (a1 > bs) { bs = a1; bk = 1; }
      if (a2 > bs) { bs = a2; bk = 2; }
      if (a3 > bs) { bs = a3; bk = 3; }
      float s1 = bs; int j1 = bk * 1024 + t;
      wave_comb64(s1, j1);
      int ju = __builtin_amdgcn_readlane(j1, 63);
      if ((ju & 1023) == t) {
        int ex = ju >> 10;
        if (ex == 0) a0 = NEGF; else if (ex == 1) a1 = NEGF;
        else if (ex == 2) a2 = NEGF; else a3 = NEGF;
      }
      if (lane == 63) { pub_s[w * 4 + r] = s1; pub_j[w * 4 + r] = j1; }
    }
  };

  publish4();

  int total = 0;
  while (true) {
    __syncthreads();
    if (w == 0) {
      float es = pub_s[lane];
      int   ej = pub_j[lane];
      float4 eb = s_box[ej];
      float ear = (eb.z - eb.x) * (eb.w - eb.y);
      bool  eav = (es >= CONF_T);
      float hv = ((lane & 3) == 3) ? es : NEGF;
      wave_fmax64(hv);
      const float H = rl_f(hv, 63);
      int Rr = 0, dn = 0;
      while (true) {
        float cs = eav ? es : NEGF;
        int   cj = eav ? ej : 0x7fffffff;
        wave_comb64(cs, cj);
        float ms = rl_f(cs, 63);
        int   mj = __builtin_amdgcn_readlane(cj, 63);
        if (ms < CONF_T) { if (H < CONF_T) dn = 1; break; }
        if (Rr > 0 && !(ms > H)) break;
        if (lane == 0) { s_pkj[total + Rr] = mj; s_pks[total + Rr] = ms; }
        Rr++;
        if (total + Rr >= TDET) { dn = 1; break; }
        float4 pb = s_box[mj];
        float pa = (pb.z - pb.x) * (pb.w - pb.y);
        if (eav) {
          if (ej == mj) { eav = false; }
          else {
            float ltx = fmaxf(pb.x, eb.x);
            float lty = fmaxf(pb.y, eb.y);
            float rbv = fminf(pb.z, eb.z);
            float rby = fminf(pb.w, eb.w);
            float wx = fmaxf(rbv - ltx, 0.0f);
            float wy = fmaxf(rby - lty, 0.0f);
            float inter = wx * wy;
            if (inter > 0.0f) {
              float iou = inter / ((pa + ear) - inter);
              if (iou > 0.5f) { eav = false; }
              else {
                es = es * expf((-10.0f * iou) * iou);
                if (es < CONF_T) eav = false;
              }
            }
          }
        }
      }
      if (lane == 0) { s_info[0] = Rr; s_info[1] = dn; }
    }
    __syncthreads();

    const int Rr = s_info[0];
    const int dn = s_info[1];
    for (int r = 0; r < Rr; ++r) {
      const int jp = s_pkj[total + r];
      float4 pb = s_box[jp];
      float pa = (pb.z - pb.x) * (pb.w - pb.y);
      #pragma unroll
      for (int k = 0; k < 4; ++k) {
        float s = rsc[k];
        if (s == NEGF) continue;
        if (k * 1024 + t == jp) { rsc[k] = NEGF; continue; }
        float ltx = fmaxf(pb.x, rbx[k].x);
        float lty = fmaxf(pb.y, rbx[k].y);
        float rbv = fminf(pb.z, rbx[k].z);
        float rby = fminf(pb.w, rbx[k].w);
        float wx = fmaxf(rbv - ltx, 0.0f);
        float wy = fmaxf(rby - lty, 0.0f);
        float inter = wx * wy;
        if (inter > 0.0f) {
          float iou = inter / ((pa + rar[k]) - inter);
          float ns;
          if (iou > 0.5f) ns = NEGF;
          else {
            ns = s * expf((-10.0f * iou) * iou);
            if (ns < CONF_T) ns = NEGF;
          }
          rsc[k] = ns;
        }
      }
    }
    total += Rr;
    if (dn) break;
    publish4();
  }

  float* ob  = out_box  + (size_t)bc * TDET * 4;
  float* osc = out_sc   + (size_t)bc * TDET;
  int*   opk = out_pick + (size_t)bc * TDET;
  if (t < TDET) {
    if (t < total) {
      int jp = s_pkj[t];
      float4 pb = s_box[jp];
      ob[t * 4 + 0] = pb.x; ob[t * 4 + 1] = pb.y;
      ob[t * 4 + 2] = pb.z; ob[t * 4 + 3] = pb.w;
      osc[t] = s_pks[t];
      opk[t] = 1;
    } else {
      opk[t] = 0;
    }
  }
}

// ---------------- K5: per-batch compaction + stable top-100 (bitonic) ----------------
__global__ __launch_bounds__(1024) void k_post(
    const float* __restrict__ out_box, const float* __restrict__ out_sc,
    const int* __restrict__ out_pick,
    float* __restrict__ out, int B)
{
  #pragma clang fp contract(off)
  const int b = blockIdx.x;
  const int t = threadIdx.x;

  __shared__ float p_sc[MTOT];
  __shared__ float p_bx[MTOT * 4];
  __shared__ unsigned char p_v[MTOT];
  __shared__ float q_sc[MTOT];
  __shared__ short q_m[MTOT];
  __shared__ int s_wtot[16];
  __shared__ unsigned long long s_key[2048];

  for (int m = t; m < MTOT; m += 1024) {
    int c = m / TDET, tt = m % TDET;
    int lanebc = b * NCLS + c;
    int pk = out_pick[(size_t)lanebc * TDET + tt];
    p_v[m] = (unsigned char)pk;
    if (pk) {
      p_sc[m] = out_sc[(size_t)lanebc * TDET + tt];
      p_bx[m * 4 + 0] = out_box[((size_t)lanebc * TDET + tt) * 4 + 0];
      p_bx[m * 4 + 1] = out_box[((size_t)lanebc * TDET + tt) * 4 + 1];
      p_bx[m * 4 + 2] = out_box[((size_t)lanebc * TDET + tt) * 4 + 2];
      p_bx[m * 4 + 3] = out_box[((size_t)lanebc * TDET + tt) * 4 + 3];
    } else {
      p_sc[m] = 0.0f;
      p_bx[m * 4 + 0] = 0.0f; p_bx[m * 4 + 1] = 0.0f;
      p_bx[m * 4 + 2] = 0.0f; p_bx[m * 4 + 3] = 0.0f;
    }
  }
  __syncthreads();

  int running = 0;
  for (int base = 0; base < MTOT; base += 1024) {
    int m = base + t;
    bool v = (m < MTOT) && p_v[m];
    unsigned long long ball = __ballot(v);
    int lane = t & 63, w = t >> 6;
    if (lane == 0) s_wtot[w] = __popcll(ball);
    __syncthreads();
    int off = 0, tot = 0;
    #pragma unroll
    for (int i = 0; i < 16; ++i) {
      int ci = s_wtot[i];
      if (i < w) off += ci;
      tot += ci;
    }
    if (v) {
      int wpre = __popcll(ball & ((1ull << lane) - 1ull));
      int j = running + off + wpre;
      q_sc[j] = p_sc[m];
      q_m[j] = (short)m;
    }
    running += tot;
    __syncthreads();
  }
  int nv = running;
  bool over = nv > TDET;

  if (over) {
    for (int e = t; e < 2048; e += 1024) {
      unsigned long long kk = 0;
      if (e < nv) {
        unsigned int sb = __float_as_uint(q_sc[e]);
        kk = ((unsigned long long)sb << 32) | (unsigned int)(~e);
      }
      s_key[e] = ~kk;
    }
    for (int kk2 = 2; kk2 <= 2048; kk2 <<= 1) {
      for (int j = kk2 >> 1; j > 0; j >>= 1) {
        __syncthreads();
        int e = ((t & ~(j - 1)) << 1) | (t & (j - 1));
        int q = e | j;
        unsigned long long a = s_key[e], bb = s_key[q];
        bool up = ((e & kk2) == 0);
        bool sw = up ? (a > bb) : (a < bb);
        if (sw) { s_key[e] = bb; s_key[q] = a; }
      }
    }
    __syncthreads();
  }

  int vd = nv < TDET ? nv : TDET;
  int base_box = B;
  int base_sc  = B + B * TDET * 4;
  int base_cl  = base_sc + B * TDET;
  if (t == 0) out[b] = (float)vd;
  if (t < TDET) {
    float sc = 0.0f, cl = -1.0f, b0 = 0.0f, b1 = 0.0f, b2 = 0.0f, b3 = 0.0f;
    int p = -1;
    if (t < nv) p = over ? (int)(unsigned int)s_key[t] : t;
    if (p >= 0) {
      int m = q_m[p];
      sc = q_sc[p];
      cl = (float)(m / TDET);
      b0 = p_bx[m * 4 + 0]; b1 = p_bx[m * 4 + 1];
      b2 = p_bx[m * 4 + 2]; b3 = p_bx[m * 4 + 3];
    }
    int o = b * TDET + t;
    out[base_box + o * 4 + 0] = b0;
    out[base_box + o * 4 + 1] = b1;
    out[base_box + o * 4 + 2] = b2;
    out[base_box + o * 4 + 3] = b3;
    out[base_sc + o] = sc;
    out[base_cl + o] = cl;
  }
}

extern "C" void kernel_launch(void* const* d_in, const int* in_sizes, int n_in,
                              void* d_out, int out_size, void* d_ws, size_t ws_size,
                              hipStream_t stream) {
  const float* pred = (const float*)d_in[0];
  const float* anch = (const float*)d_in[1];
  int N  = in_sizes[1] / 4;       // 49104
  int BN = in_sizes[0] / 20;      // B*N
  int B  = BN / N;                // 4
  int nchunk = (N + 255) / 256;   // 192
  int NBC = B * NCLS;             // 64

  char* ws = (char*)d_ws;
  size_t off = 0;
  // float4-accessed arrays first (16B alignment)
  float* candbx = (float*)(ws + off); off += (size_t)NBC * CAP * 4 * sizeof(float);
  float* obox   = (float*)(ws + off); off += (size_t)NBC * TDET * 4 * sizeof(float);
  float* score  = (float*)(ws + off); off += (size_t)BN * sizeof(float);
  float* candsc = (float*)(ws + off); off += (size_t)NBC * CAP * sizeof(float);
  float* osc    = (float*)(ws + off); off += (size_t)NBC * TDET * sizeof(float);
  int*   cls    = (int*)(ws + off);   off += (size_t)BN * sizeof(int);
  int*   counts = (int*)(ws + off);   off += (size_t)NBC * nchunk * sizeof(int);
  int*   ktot   = (int*)(ws + off);   off += (size_t)NBC * sizeof(int);
  int*   opick  = (int*)(ws + off);   off += (size_t)NBC * TDET * sizeof(int);
  int*   flagOK = (int*)(ws + off);   off += (size_t)NBC * sizeof(int);

  k_decode<<<B * nchunk, 256, 0, stream>>>(pred, score, cls, counts, N, nchunk);
  k_scatter<<<B * nchunk, 256, 0, stream>>>(pred, anch, score, cls, counts,
                                            candsc, candbx, ktot, N, nchunk);
  k_nms<<<NBC, 512, 0, stream>>>(candsc, candbx, ktot, obox, osc, opick, flagOK);
  k_nms_full<<<NBC, 1024, 0, stream>>>(candsc, candbx, ktot, flagOK, obox, osc, opick);
  k_post<<<B, 1024, 0, stream>>>(obox, osc, opick, (float*)d_out, B);
}

// Round 19
// 122.836 us; speedup vs baseline: 2.2449x; 1.1049x over previous
//
#include <hip/hip_runtime.h>
#include <math.h>

#define CONF_T 0.05f
#define NEGF  -1e10f
#define NCLS 16
#define TDET 100
#define CAP 4096
#define MSEL 512
#define MTOT (NCLS*TDET)    // 1600

template<int CTRL>
__device__ __forceinline__ void dpp_comb(float& s, int& j) {
  int si_ = __builtin_amdgcn_update_dpp(__float_as_int(s), __float_as_int(s),
                                        CTRL, 0xf, 0xf, false);
  int ji_ = __builtin_amdgcn_update_dpp(j, j, CTRL, 0xf, 0xf, false);
  float si = __int_as_float(si_);
  bool take = (si > s) || (si == s && ji_ < j);
  s = take ? si : s;
  j = take ? ji_ : j;
}
template<int CTRL>
__device__ __forceinline__ void dpp_max1(float& s) {
  int si_ = __builtin_amdgcn_update_dpp(__float_as_int(s), __float_as_int(s),
                                        CTRL, 0xf, 0xf, false);
  s = fmaxf(s, __int_as_float(si_));
}
template<int CTRL, int RM, bool BC>
__device__ __forceinline__ int dpp_mov0(int v) {
  return __builtin_amdgcn_update_dpp(0, v, CTRL, RM, 0xf, BC);
}
#define ROW_SHR1  0x111
#define ROW_SHR2  0x112
#define ROW_SHR4  0x114
#define ROW_SHR8  0x118
#define ROW_BC15  0x142
#define ROW_BC31  0x143

__device__ __forceinline__ void wave_comb64(float& s, int& j) {
  dpp_comb<ROW_SHR1>(s, j);
  dpp_comb<ROW_SHR2>(s, j);
  dpp_comb<ROW_SHR4>(s, j);
  dpp_comb<ROW_SHR8>(s, j);
  dpp_comb<ROW_BC15>(s, j);
  dpp_comb<ROW_BC31>(s, j);
}
__device__ __forceinline__ void wave_fmax64(float& s) {
  dpp_max1<ROW_SHR1>(s);
  dpp_max1<ROW_SHR2>(s);
  dpp_max1<ROW_SHR4>(s);
  dpp_max1<ROW_SHR8>(s);
  dpp_max1<ROW_BC15>(s);
  dpp_max1<ROW_BC31>(s);
}
__device__ __forceinline__ float rl_f(float v, int l) {
  return __int_as_float(__builtin_amdgcn_readlane(__float_as_int(v), l));
}

// ---------------- K1: class/score + per-chunk class counts (no box decode) ----------------
__global__ __launch_bounds__(256) void k_decode(
    const float* __restrict__ pred,
    float* __restrict__ score, int* __restrict__ cls,
    int* __restrict__ counts, int N, int nchunk)
{
  #pragma clang fp contract(off)
  const int b = blockIdx.x / nchunk;
  const int chunk = blockIdx.x % nchunk;
  const int t = threadIdx.x;
  const int n = chunk * 256 + t;

  __shared__ int hist[NCLS];
  if (t < NCLS) hist[t] = 0;
  __syncthreads();

  int v = -1;
  if (n < N) {
    const size_t i = (size_t)b * N + n;
    const float4* p4 = reinterpret_cast<const float4*>(pred + i * 20);
    float4 v1 = p4[1], v2 = p4[2], v3 = p4[3], v4 = p4[4];
    float lg[NCLS] = {v1.x, v1.y, v1.z, v1.w, v2.x, v2.y, v2.z, v2.w,
                      v3.x, v3.y, v3.z, v3.w, v4.x, v4.y, v4.z, v4.w};
    float best = -1.0f; int bi = 0;
    #pragma unroll
    for (int c = 0; c < NCLS; ++c) {
      float s = 1.0f / (1.0f + expf(-lg[c]));
      if (s > best) { best = s; bi = c; }
    }
    score[i] = best;
    v = (best >= CONF_T) ? bi : -1;
    cls[i] = v;
  }

  int lane = t & 63;
  #pragma unroll
  for (int c = 0; c < NCLS; ++c) {
    unsigned long long bl = __ballot(v == c);
    if (lane == 0 && bl) atomicAdd(&hist[c], __popcll(bl));
  }
  __syncthreads();
  if (t < NCLS) counts[(b * NCLS + t) * nchunk + chunk] = hist[t];
}

// ---------------- K2: stable scatter (fused scan) + on-the-fly box decode ----------------
__global__ __launch_bounds__(256) void k_scatter(
    const float* __restrict__ pred, const float* __restrict__ anch,
    const float* __restrict__ score, const int* __restrict__ cls,
    const int* __restrict__ counts,
    float* __restrict__ cand_sc, float* __restrict__ cand_bx, int* __restrict__ ktot,
    int N, int nchunk)
{
  #pragma clang fp contract(off)
  const int b = blockIdx.x / nchunk;
  const int chunk = blockIdx.x % nchunk;
  const int t = threadIdx.x;
  const int n = chunk * 256 + t;

  __shared__ int s_part[NCLS][17];
  __shared__ int s_ptot[NCLS][17];
  __shared__ int s_off[NCLS];
  __shared__ int wcnt[4][NCLS];

  {
    int c = t >> 4, part = t & 15;
    int su = 0, tot = 0;
    for (int ch = part; ch < nchunk; ch += 16) {
      int vv = counts[(b * NCLS + c) * nchunk + ch];
      tot += vv;
      su += (ch < chunk) ? vv : 0;
    }
    s_part[c][part] = su;
    s_ptot[c][part] = tot;
  }
  __syncthreads();
  if (t < NCLS) {
    int su = 0, tot = 0;
    #pragma unroll
    for (int i = 0; i < 16; ++i) { su += s_part[t][i]; tot += s_ptot[t][i]; }
    s_off[t] = su;
    if (chunk == 0) ktot[b * NCLS + t] = tot;
  }

  int v = (n < N) ? cls[(size_t)b * N + n] : -1;
  int lane = t & 63, w = t >> 6;
  int myrank = 0;
  #pragma unroll
  for (int c = 0; c < NCLS; ++c) {
    unsigned long long bl = __ballot(v == c);
    if (lane == 0) wcnt[w][c] = __popcll(bl);
    if (v == c) myrank = __popcll(bl & ((1ull << lane) - 1ull));
  }
  __syncthreads();
  if (v >= 0) {
    int pre = 0;
    #pragma unroll
    for (int i = 0; i < 4; ++i) if (i < w) pre += wcnt[i][v];
    int pos = s_off[v] + pre + myrank;
    if (pos < CAP) {
      const size_t i = (size_t)b * N + n;
      float4 p0 = *reinterpret_cast<const float4*>(pred + i * 20);
      float4 a = reinterpret_cast<const float4*>(anch)[n];  // cx, cy, w, h
      float xx = p0.x * a.z + a.x;
      float yy = p0.y * a.w + a.y;
      float wx = expf(p0.z) * a.z;
      float wy = expf(p0.w) * a.w;
      float hx = 0.5f * wx, hy = 0.5f * wy;
      float4 bx;
      bx.x = xx - hx; bx.y = yy - hy; bx.z = xx + hx; bx.w = yy + hy;
      int bc = b * NCLS + v;
      cand_sc[(size_t)bc * CAP + pos] = score[i];
      reinterpret_cast<float4*>(cand_bx)[(size_t)bc * CAP + pos] = bx;
    }
  }
}

// ---------------- K3: FUSED select + 8-wave 1-slot NMS (round-16 pub layout) ----------------
__global__ __launch_bounds__(512) void k_nms(
    const float* __restrict__ cand_sc, const float* __restrict__ cand_bx,
    const int* __restrict__ ktot,
    float* __restrict__ out_box, float* __restrict__ out_sc, int* __restrict__ out_pick,
    int* __restrict__ flagOK)
{
  #pragma clang fp contract(off)
  const int bc = blockIdx.x;
  const int t = threadIdx.x;
  const int lane = t & 63, w = t >> 6;

  __shared__ int    hist[4096];
  __shared__ int    s_wsum[8];
  __shared__ int    s_T, s_thrbits;
  __shared__ int    s_cc[8][8];
  __shared__ float  s_csc[MSEL];
  __shared__ float4 sbx[MSEL];
  __shared__ float4 pubA[2][8];      // {score, j(bits), x1, y1}
  __shared__ float2 pubB[2][8];      // {x2, y2}
  __shared__ int    s_pk[TDET];
  __shared__ float  s_ps[TDET];

  int K = ktot[bc]; if (K > CAP) K = CAP;

  // ---- select phase ----
  for (int i = t; i < 4096; i += 512) hist[i] = 0;
  if (t == 0) { s_T = 4096; s_thrbits = 0; }
  __syncthreads();                                   // (1)

  float sc[8]; int key[8];
  #pragma unroll
  for (int k = 0; k < 8; ++k) {
    int j = k * 512 + t;
    if (j < K) {
      sc[k] = cand_sc[(size_t)bc * CAP + j];
      int bits = __float_as_int(sc[k]);
      int kk = (bits >> 11) - 0x7E000;          // [0.5,1.0) -> 0..4095, monotone
      kk = kk < 0 ? 0 : (kk > 4095 ? 4095 : kk);
      key[k] = kk;
      atomicAdd(&hist[kk], 1);
    } else { key[k] = -1; sc[k] = 0.0f; }
  }
  __syncthreads();                                   // (2)

  int h[8]; int loc = 0;
  #pragma unroll
  for (int u = 0; u < 8; ++u) { h[u] = hist[8 * t + u]; loc += h[u]; }
  int pf = loc;
  pf += dpp_mov0<ROW_SHR1, 0xf, true >(pf);
  pf += dpp_mov0<ROW_SHR2, 0xf, true >(pf);
  pf += dpp_mov0<ROW_SHR4, 0xf, true >(pf);
  pf += dpp_mov0<ROW_SHR8, 0xf, true >(pf);
  pf += dpp_mov0<ROW_BC15, 0xa, false>(pf);
  pf += dpp_mov0<ROW_BC31, 0xc, false>(pf);
  if (lane == 63) s_wsum[w] = pf;
  __syncthreads();                                   // (3)
  int base = 0, Kall = 0;
  #pragma unroll
  for (int i = 0; i < 8; ++i) {
    int v = s_wsum[i];
    Kall += v;
    if (i < w) base += v;
  }
  {
    int cLE = base + pf;                 // count of keys in bins <= 8t+7
    int run = Kall - (cLE - loc);        // cntGE(bin 8t)
    int cand = 0x7fffffff;
    #pragma unroll
    for (int u = 0; u < 8; ++u) {
      if (cand == 0x7fffffff && run <= MSEL) cand = 8 * t + u;
      run -= h[u];
    }
    if (cand != 0x7fffffff) atomicMin(&s_T, cand);
  }
  __syncthreads();                                   // (4)
  const int T = s_T;

  unsigned long long bl0, bl1, bl2, bl3, bl4, bl5, bl6, bl7;
  #define KEEPP(k) ((key[k] >= 0) && (key[k] >= T))
  bl0 = __ballot(KEEPP(0)); bl1 = __ballot(KEEPP(1));
  bl2 = __ballot(KEEPP(2)); bl3 = __ballot(KEEPP(3));
  bl4 = __ballot(KEEPP(4)); bl5 = __ballot(KEEPP(5));
  bl6 = __ballot(KEEPP(6)); bl7 = __ballot(KEEPP(7));
  if (lane == 0) {
    s_cc[w][0] = __popcll(bl0); s_cc[w][1] = __popcll(bl1);
    s_cc[w][2] = __popcll(bl2); s_cc[w][3] = __popcll(bl3);
    s_cc[w][4] = __popcll(bl4); s_cc[w][5] = __popcll(bl5);
    s_cc[w][6] = __popcll(bl6); s_cc[w][7] = __popcll(bl7);
  }
  #pragma unroll
  for (int k = 0; k < 8; ++k)
    if (key[k] >= 0 && key[k] < T) atomicMax(&s_thrbits, __float_as_int(sc[k]));
  __syncthreads();                                   // (5)

  int runpos = 0;
  #pragma unroll
  for (int k = 0; k < 8; ++k) {
    int pre = 0, tot = 0;
    #pragma unroll
    for (int i = 0; i < 8; ++i) {
      int c = s_cc[i][k];
      tot += c;
      if (i < w) pre += c;
    }
    unsigned long long blk = (k == 0) ? bl0 : (k == 1) ? bl1 : (k == 2) ? bl2 :
                             (k == 3) ? bl3 : (k == 4) ? bl4 : (k == 5) ? bl5 :
                             (k == 6) ? bl6 : bl7;
    if (KEEPP(k)) {
      int pos = runpos + pre + __popcll(blk & ((1ull << lane) - 1ull));
      s_csc[pos] = sc[k];
      sbx[pos] = reinterpret_cast<const float4*>(cand_bx)[(size_t)bc * CAP + k * 512 + t];
    }
    runpos += tot;
  }
  #undef KEEPP
  const int KM = runpos;                  // uniform, <= MSEL
  const float thr = (T == 0) ? -1e30f : __int_as_float(s_thrbits);
  __syncthreads();                                   // (6)

  // ---- NMS phase: ONE candidate per thread ----
  float  rsc0; float4 rbx0; float rar0;
  if (t < KM) {
    rsc0 = s_csc[t];
    rbx0 = sbx[t];
    rar0 = (rbx0.z - rbx0.x) * (rbx0.w - rbx0.y);
  } else {
    rsc0 = NEGF;
    rbx0.x = rbx0.y = rbx0.z = rbx0.w = 0.0f;
    rar0 = 0.0f;
  }

  // publish: (max score, min t) per wave; j == t lane-ordered -> ctz(ballot)
  auto publish = [&](int par) {
    float sm = rsc0;
    wave_fmax64(sm);
    const float smu = rl_f(sm, 63);
    unsigned long long msk = __ballot(rsc0 == smu);
    const int jp = (w << 6) | (int)__builtin_ctzll(msk);
    if (t == jp) {
      float4 ra; ra.x = smu; ra.y = __int_as_float(jp); ra.z = rbx0.x; ra.w = rbx0.y;
      pubA[par][w] = ra;
      float2 r2; r2.x = rbx0.z; r2.y = rbx0.w;
      pubB[par][w] = r2;
    }
  };

  publish(0);

  bool ok = true, early = false;
  int total = 0;
  for (int iter = 0; iter < TDET; ++iter) {
    __syncthreads();                       // the ONLY barrier per iteration
    const int par = iter & 1;

    float4 ra = pubA[par][lane & 7];       // broadcast-friendly: 8 addrs/wave
    float2 r2 = pubB[par][lane & 7];
    // fmax over the 8 records; ROW_SHR moves toward higher lanes: lane 7 =
    // max of records 0..7 within each 8-lane replica group of row 0..15.
    float m = ra.x;
    dpp_max1<ROW_SHR1>(m);
    dpp_max1<ROW_SHR2>(m);
    dpp_max1<ROW_SHR4>(m);
    const float ms = rl_f(m, 7);
    if (ms < CONF_T) { early = true; break; }
    ok = ok && (ms > thr);                 // exactness guard vs excluded set

    const int r = (int)__builtin_ctzll(__ballot(ra.x == ms));   // record idx 0..7
    const int mj = __builtin_amdgcn_readlane(__float_as_int(ra.y), r);
    const float px = rl_f(ra.z, r);
    const float py = rl_f(ra.w, r);
    const float pz = rl_f(r2.x, r);
    const float pw = rl_f(r2.y, r);
    if (t == 0) { s_pk[iter] = mj; s_ps[iter] = ms; }
    total = iter + 1;
    const float pa = (pz - px) * (pw - py);

    if (rsc0 != NEGF) {
      if (t == mj) {
        rsc0 = NEGF;
      } else if (!(px > rbx0.z || pz < rbx0.x || py > rbx0.w || pw < rbx0.y)) {
        float ltx = fmaxf(px, rbx0.x);
        float lty = fmaxf(py, rbx0.y);
        float rbv = fminf(pz, rbx0.z);
        float rby = fminf(pw, rbx0.w);
        float wx = fmaxf(rbv - ltx, 0.0f);
        float wy = fmaxf(rby - lty, 0.0f);
        float inter = wx * wy;
        if (inter > 0.0f) {                // inter==0 => score bit-identical
          float iou = inter / ((pa + rar0) - inter);
          float ns;
          if (iou > 0.5f) ns = NEGF;
          else {
            ns = rsc0 * expf((-10.0f * iou) * iou);
            if (ns < CONF_T) ns = NEGF;    // pruning: output-equivalent
          }
          rsc0 = ns;
        }
      }
    }

    publish(par ^ 1);
  }
  if (early) ok = ok && (thr < CONF_T);

  __syncthreads();                          // s_pk/s_ps visible to all
  float* ob  = out_box  + (size_t)bc * TDET * 4;
  float* osc = out_sc   + (size_t)bc * TDET;
  int*   opk = out_pick + (size_t)bc * TDET;
  for (int rr = total + t; rr < TDET; rr += 512) opk[rr] = 0;
  if (t < total) {                          // total <= 100 < 512
    int jp = s_pk[t];
    float4 pb = sbx[jp];
    ob[t * 4 + 0] = pb.x; ob[t * 4 + 1] = pb.y;
    ob[t * 4 + 2] = pb.z; ob[t * 4 + 3] = pb.w;
    osc[t] = s_ps[t];
    opk[t] = 1;
  }
  if (t == 0) flagOK[bc] = ok ? 1 : 0;
}

// ---------------- K4: repair — exact batched NMS, gated on flag ----------------
__global__ __launch_bounds__(1024) void k_nms_full(
    const float* __restrict__ cand_sc, const float* __restrict__ cand_bx,
    const int* __restrict__ ktot, const int* __restrict__ flagOK,
    float* __restrict__ out_box, float* __restrict__ out_sc, int* __restrict__ out_pick)
{
  #pragma clang fp contract(off)
  const int bc = blockIdx.x;
  if (flagOK[bc]) return;
  const int t = threadIdx.x;
  const int lane = t & 63, w = t >> 6;

  __shared__ float4 s_box[CAP];
  __shared__ float  pub_s[64];
  __shared__ int    pub_j[64];
  __shared__ int    s_pkj[TDET];
  __shared__ float  s_pks[TDET];
  __shared__ int    s_info[2];

  int K = ktot[bc]; if (K > CAP) K = CAP;

  float  rsc[4];
  float4 rbx[4];
  float  rar[4];
  #pragma unroll
  for (int k = 0; k < 4; ++k) {
    int j = k * 1024 + t;
    if (j < K) {
      rsc[k] = cand_sc[(size_t)bc * CAP + j];
      float4 bb = reinterpret_cast<const float4*>(cand_bx)[(size_t)bc * CAP + j];
      rbx[k] = bb;
      s_box[j] = bb;
      rar[k] = (bb.z - bb.x) * (bb.w - bb.y);
    } else {
      rsc[k] = NEGF;
      rbx[k].x = rbx[k].y = rbx[k].z = rbx[k].w = 0.0f;
      float4 z; z.x = z.y = z.z = z.w = 0.0f;
      s_box[j] = z;
      rar[k] = 0.0f;
    }
  }

  auto publish4 = [&]() {
    float a0 = rsc[0], a1 = rsc[1], a2 = rsc[2], a3 = rsc[3];
    #pragma unroll
    for (int r = 0; r < 4; ++r) {
      float bs = a0; int bk = 0;
      if (a1 > bs) { bs = a1; bk = 1; }
      if (a2 > bs) { bs = a2; bk = 2; }
      if (a3 > bs) { bs = a3; bk = 3; }
      float s1 = bs; int j1 = bk * 1024 + t;
      wave_comb64(s1, j1);
      int ju = __builtin_amdgcn_readlane(j1, 63);
      if ((ju & 1023) == t) {
        int ex = ju >> 10;
        if (ex == 0) a0 = NEGF; else if (ex == 1) a1 = NEGF;
        else if (ex == 2) a2 = NEGF; else a3 = NEGF;
      }
      if (lane == 63) { pub_s[w * 4 + r] = s1; pub_j[w * 4 + r] = j1; }
    }
  };

  publish4();

  int total = 0;
  while (true) {
    __syncthreads();
    if (w == 0) {
      float es = pub_s[lane];
      int   ej = pub_j[lane];
      float4 eb = s_box[ej];
      float ear = (eb.z - eb.x) * (eb.w - eb.y);
      bool  eav = (es >= CONF_T);
      float hv = ((lane & 3) == 3) ? es : NEGF;
      wave_fmax64(hv);
      const float H = rl_f(hv, 63);
      int Rr = 0, dn = 0;
      while (true) {
        float cs = eav ? es : NEGF;
        int   cj = eav ? ej : 0x7fffffff;
        wave_comb64(cs, cj);
        float ms = rl_f(cs, 63);
        int   mj = __builtin_amdgcn_readlane(cj, 63);
        if (ms < CONF_T) { if (H < CONF_T) dn = 1; break; }
        if (Rr > 0 && !(ms > H)) break;
        if (lane == 0) { s_pkj[total + Rr] = mj; s_pks[total + Rr] = ms; }
        Rr++;
        if (total + Rr >= TDET) { dn = 1; break; }
        float4 pb = s_box[mj];
        float pa = (pb.z - pb.x) * (pb.w - pb.y);
        if (eav) {
          if (ej == mj) { eav = false; }
          else {
            float ltx = fmaxf(pb.x, eb.x);
            float lty = fmaxf(pb.y, eb.y);
            float rbv = fminf(pb.z, eb.z);
            float rby = fminf(pb.w, eb.w);
            float wx = fmaxf(rbv - ltx, 0.0f);
            float wy = fmaxf(rby - lty, 0.0f);
            float inter = wx * wy;
            if (inter > 0.0f) {
              float iou = inter / ((pa + ear) - inter);
              if (iou > 0.5f) { eav = false; }
              else {
                es = es * expf((-10.0f * iou) * iou);
                if (es < CONF_T) eav = false;
              }
            }
          }
        }
      }
      if (lane == 0) { s_info[0] = Rr; s_info[1] = dn; }
    }
    __syncthreads();

    const int Rr = s_info[0];
    const int dn = s_info[1];
    for (int r = 0; r < Rr; ++r) {
      const int jp = s_pkj[total + r];
      float4 pb = s_box[jp];
      float pa = (pb.z - pb.x) * (pb.w - pb.y);
      #pragma unroll
      for (int k = 0; k < 4; ++k) {
        float s = rsc[k];
        if (s == NEGF) continue;
        if (k * 1024 + t == jp) { rsc[k] = NEGF; continue; }
        float ltx = fmaxf(pb.x, rbx[k].x);
        float lty = fmaxf(pb.y, rbx[k].y);
        float rbv = fminf(pb.z, rbx[k].z);
        float rby = fminf(pb.w, rbx[k].w);
        float wx = fmaxf(rbv - ltx, 0.0f);
        float wy = fmaxf(rby - lty, 0.0f);
        float inter = wx * wy;
        if (inter > 0.0f) {
          float iou = inter / ((pa + rar[k]) - inter);
          float ns;
          if (iou > 0.5f) ns = NEGF;
          else {
            ns = s * expf((-10.0f * iou) * iou);
            if (ns < CONF_T) ns = NEGF;
          }
          rsc[k] = ns;
        }
      }
    }
    total += Rr;
    if (dn) break;
    publish4();
  }

  float* ob  = out_box  + (size_t)bc * TDET * 4;
  float* osc = out_sc   + (size_t)bc * TDET;
  int*   opk = out_pick + (size_t)bc * TDET;
  if (t < TDET) {
    if (t < total) {
      int jp = s_pkj[t];
      float4 pb = s_box[jp];
      ob[t * 4 + 0] = pb.x; ob[t * 4 + 1] = pb.y;
      ob[t * 4 + 2] = pb.z; ob[t * 4 + 3] = pb.w;
      osc[t] = s_pks[t];
      opk[t] = 1;
    } else {
      opk[t] = 0;
    }
  }
}

// ---------------- K5: per-batch compaction + stable top-100 (bitonic) ----------------
__global__ __launch_bounds__(1024) void k_post(
    const float* __restrict__ out_box, const float* __restrict__ out_sc,
    const int* __restrict__ out_pick,
    float* __restrict__ out, int B)
{
  #pragma clang fp contract(off)
  const int b = blockIdx.x;
  const int t = threadIdx.x;

  __shared__ float p_sc[MTOT];
  __shared__ float p_bx[MTOT * 4];
  __shared__ unsigned char p_v[MTOT];
  __shared__ float q_sc[MTOT];
  __shared__ short q_m[MTOT];
  __shared__ int s_wtot[16];
  __shared__ unsigned long long s_key[2048];

  for (int m = t; m < MTOT; m += 1024) {
    int c = m / TDET, tt = m % TDET;
    int lanebc = b * NCLS + c;
    int pk = out_pick[(size_t)lanebc * TDET + tt];
    p_v[m] = (unsigned char)pk;
    if (pk) {
      p_sc[m] = out_sc[(size_t)lanebc * TDET + tt];
      p_bx[m * 4 + 0] = out_box[((size_t)lanebc * TDET + tt) * 4 + 0];
      p_bx[m * 4 + 1] = out_box[((size_t)lanebc * TDET + tt) * 4 + 1];
      p_bx[m * 4 + 2] = out_box[((size_t)lanebc * TDET + tt) * 4 + 2];
      p_bx[m * 4 + 3] = out_box[((size_t)lanebc * TDET + tt) * 4 + 3];
    } else {
      p_sc[m] = 0.0f;
      p_bx[m * 4 + 0] = 0.0f; p_bx[m * 4 + 1] = 0.0f;
      p_bx[m * 4 + 2] = 0.0f; p_bx[m * 4 + 3] = 0.0f;
    }
  }
  __syncthreads();

  int running = 0;
  for (int base = 0; base < MTOT; base += 1024) {
    int m = base + t;
    bool v = (m < MTOT) && p_v[m];
    unsigned long long ball = __ballot(v);
    int lane = t & 63, w = t >> 6;
    if (lane == 0) s_wtot[w] = __popcll(ball);
    __syncthreads();
    int off = 0, tot = 0;
    #pragma unroll
    for (int i = 0; i < 16; ++i) {
      int ci = s_wtot[i];
      if (i < w) off += ci;
      tot += ci;
    }
    if (v) {
      int wpre = __popcll(ball & ((1ull << lane) - 1ull));
      int j = running + off + wpre;
      q_sc[j] = p_sc[m];
      q_m[j] = (short)m;
    }
    running += tot;
    __syncthreads();
  }
  int nv = running;
  bool over = nv > TDET;

  if (over) {
    for (int e = t; e < 2048; e += 1024) {
      unsigned long long kk = 0;
      if (e < nv) {
        unsigned int sb = __float_as_uint(q_sc[e]);
        kk = ((unsigned long long)sb << 32) | (unsigned int)(~e);
      }
      s_key[e] = ~kk;
    }
    for (int kk2 = 2; kk2 <= 2048; kk2 <<= 1) {
      for (int j = kk2 >> 1; j > 0; j >>= 1) {
        __syncthreads();
        int e = ((t & ~(j - 1)) << 1) | (t & (j - 1));
        int q = e | j;
        unsigned long long a = s_key[e], bb = s_key[q];
        bool up = ((e & kk2) == 0);
        bool sw = up ? (a > bb) : (a < bb);
        if (sw) { s_key[e] = bb; s_key[q] = a; }
      }
    }
    __syncthreads();
  }

  int vd = nv < TDET ? nv : TDET;
  int base_box = B;
  int base_sc  = B + B * TDET * 4;
  int base_cl  = base_sc + B * TDET;
  if (t == 0) out[b] = (float)vd;
  if (t < TDET) {
    float sc = 0.0f, cl = -1.0f, b0 = 0.0f, b1 = 0.0f, b2 = 0.0f, b3 = 0.0f;
    int p = -1;
    if (t < nv) p = over ? (int)(unsigned int)s_key[t] : t;
    if (p >= 0) {
      int m = q_m[p];
      sc = q_sc[p];
      cl = (float)(m / TDET);
      b0 = p_bx[m * 4 + 0]; b1 = p_bx[m * 4 + 1];
      b2 = p_bx[m * 4 + 2]; b3 = p_bx[m * 4 + 3];
    }
    int o = b * TDET + t;
    out[base_box + o * 4 + 0] = b0;
    out[base_box + o * 4 + 1] = b1;
    out[base_box + o * 4 + 2] = b2;
    out[base_box + o * 4 + 3] = b3;
    out[base_sc + o] = sc;
    out[base_cl + o] = cl;
  }
}

extern "C" void kernel_launch(void* const* d_in, const int* in_sizes, int n_in,
                              void* d_out, int out_size, void* d_ws, size_t ws_size,
                              hipStream_t stream) {
  const float* pred = (const float*)d_in[0];
  const float* anch = (const float*)d_in[1];
  int N  = in_sizes[1] / 4;       // 49104
  int BN = in_sizes[0] / 20;      // B*N
  int B  = BN / N;                // 4
  int nchunk = (N + 255) / 256;   // 192
  int NBC = B * NCLS;             // 64

  char* ws = (char*)d_ws;
  size_t off = 0;
  // float4-accessed arrays first (16B alignment)
  float* candbx = (float*)(ws + off); off += (size_t)NBC * CAP * 4 * sizeof(float);
  float* obox   = (float*)(ws + off); off += (size_t)NBC * TDET * 4 * sizeof(float);
  float* score  = (float*)(ws + off); off += (size_t)BN * sizeof(float);
  float* candsc = (float*)(ws + off); off += (size_t)NBC * CAP * sizeof(float);
  float* osc    = (float*)(ws + off); off += (size_t)NBC * TDET * sizeof(float);
  int*   cls    = (int*)(ws + off);   off += (size_t)BN * sizeof(int);
  int*   counts = (int*)(ws + off);   off += (size_t)NBC * nchunk * sizeof(int);
  int*   ktot   = (int*)(ws + off);   off += (size_t)NBC * sizeof(int);
  int*   opick  = (int*)(ws + off);   off += (size_t)NBC * TDET * sizeof(int);
  int*   flagOK = (int*)(ws + off);   off += (size_t)NBC * sizeof(int);

  k_decode<<<B * nchunk, 256, 0, stream>>>(pred, score, cls, counts, N, nchunk);
  k_scatter<<<B * nchunk, 256, 0, stream>>>(pred, anch, score, cls, counts,
                                            candsc, candbx, ktot, N, nchunk);
  k_nms<<<NBC, 512, 0, stream>>>(candsc, candbx, ktot, obox, osc, opick, flagOK);
  k_nms_full<<<NBC, 1024, 0, stream>>>(candsc, candbx, ktot, flagOK, obox, osc, opick);
  k_post<<<B, 1024, 0, stream>>>(obox, osc, opick, (float*)d_out, B);
}